// Round 1
// baseline (288.908 us; speedup 1.0000x reference)
//
#include <hip/hip_runtime.h>
#include <hip/hip_bf16.h>
#include <stdint.h>

#define BN 8192
#define DK 1024
#define LSMOOTH 0.1f
#define EPSF 1e-7f

typedef __bf16 bf16x8 __attribute__((ext_vector_type(8)));
typedef float f32x4 __attribute__((ext_vector_type(4)));

__device__ __forceinline__ unsigned short f2bf(float f) {
  union { float f; uint32_t u; } v; v.f = f;
  uint32_t u = v.u;
  u += 0x7fffu + ((u >> 16) & 1u);   // round-to-nearest-even
  return (unsigned short)(u >> 16);
}

// ---------------- prep: f32 -> bf16 conversion + row squared norms ----------------
__global__ __launch_bounds__(256) void prep_kernel(
    const float* __restrict__ sign, const float* __restrict__ text,
    unsigned short* __restrict__ Abf, unsigned short* __restrict__ Bbf,
    float* __restrict__ xx, float* __restrict__ yy) {
  const int b = blockIdx.x;          // 0..2*BN-1
  const int row = b & (BN - 1);
  const bool isB = b >= BN;
  const float4* src = (const float4*)((isB ? text : sign) + (size_t)row * DK);
  ushort4* dst = (ushort4*)((isB ? Bbf : Abf) + (size_t)row * DK);
  const int t = threadIdx.x;         // 256 threads, 1 float4 each (DK/4 = 256)
  float4 v = src[t];
  ushort4 o;
  o.x = f2bf(v.x); o.y = f2bf(v.y); o.z = f2bf(v.z); o.w = f2bf(v.w);
  dst[t] = o;
  float ss = v.x * v.x + v.y * v.y + v.z * v.z + v.w * v.w;
  #pragma unroll
  for (int off = 32; off; off >>= 1) ss += __shfl_down(ss, off);
  __shared__ float red[4];
  if ((t & 63) == 0) red[t >> 6] = ss;
  __syncthreads();
  if (t == 0) (isB ? yy : xx)[row] = red[0] + red[1] + red[2] + red[3];
}

// ---------------- fused GEMM + poincare-dist + online score reductions ----------------
// 128x128 tile, BK=64, 4 waves (2x2), 16x16x32 bf16 MFMA, global_load_lds staging
// with pre-swizzled global source + XOR-swizzled ds_read (T2, rule #21 both-sides).
__global__ __launch_bounds__(256, 2) void gemm_fused(
    const unsigned short* __restrict__ Abf, const unsigned short* __restrict__ Bbf,
    const float* __restrict__ xx, const float* __restrict__ yy,
    const float* __restrict__ p_log_tau, const float* __restrict__ p_margin,
    float* __restrict__ row_sumexp, float* __restrict__ accums) {
  __shared__ __align__(16) char ldsA[16384];   // 128 rows x 64 bf16 (128 B/row)
  __shared__ __align__(16) char ldsB[16384];
  __shared__ float red[4][3];

  const int tid = threadIdx.x;
  const int wave = tid >> 6, lane = tid & 63;
  const int l15 = lane & 15, g4 = lane >> 4;
  const int blockRow = blockIdx.y * 128;
  const int blockCol = blockIdx.x * 128;
  const int waveM = wave >> 1, waveN = wave & 1;

  f32x4 acc[4][4];
  #pragma unroll
  for (int m = 0; m < 4; ++m)
    #pragma unroll
    for (int n = 0; n < 4; ++n)
      acc[m][n] = (f32x4){0.f, 0.f, 0.f, 0.f};

  // staging geometry: per call, 256 threads cover 32 rows x 64 k (16 B per lane).
  // linear LDS byte for thread t is t*16; global source is inverse-swizzled so the
  // swizzled ds_read below sees A[row][k].
  const int srow = tid >> 3;                                   // row within call (0..31)
  const int inrow = ((tid & 7) * 16) ^ ((srow & 7) << 4);      // swizzled byte-in-row

  for (int kt = 0; kt < DK / 64; ++kt) {
    const int k0 = kt * 64;
    #pragma unroll
    for (int c = 0; c < 4; ++c) {
      const int rowA = c * 32 + srow;                          // (rowA&7)==(srow&7)
      const unsigned short* gA = Abf + (size_t)(blockRow + rowA) * DK + k0 + (inrow >> 1);
      const unsigned short* gB = Bbf + (size_t)(blockCol + rowA) * DK + k0 + (inrow >> 1);
      char* lA = ldsA + c * 4096 + wave * 1024;                // wave-uniform base
      char* lB = ldsB + c * 4096 + wave * 1024;
      __builtin_amdgcn_global_load_lds((const __attribute__((address_space(1))) void*)gA,
                                       (__attribute__((address_space(3))) void*)lA, 16, 0, 0);
      __builtin_amdgcn_global_load_lds((const __attribute__((address_space(1))) void*)gB,
                                       (__attribute__((address_space(3))) void*)lB, 16, 0, 0);
    }
    __syncthreads();
    #pragma unroll
    for (int kk = 0; kk < 2; ++kk) {
      bf16x8 afrag[4], bfrag[4];
      #pragma unroll
      for (int m = 0; m < 4; ++m) {
        const int r = waveM * 64 + m * 16 + l15;
        const int byte = (r * 128 + kk * 64 + g4 * 16) ^ ((r & 7) << 4);
        afrag[m] = *(const bf16x8*)(ldsA + byte);
      }
      #pragma unroll
      for (int n = 0; n < 4; ++n) {
        const int r = waveN * 64 + n * 16 + l15;
        const int byte = (r * 128 + kk * 64 + g4 * 16) ^ ((r & 7) << 4);
        bfrag[n] = *(const bf16x8*)(ldsB + byte);
      }
      #pragma unroll
      for (int m = 0; m < 4; ++m)
        #pragma unroll
        for (int n = 0; n < 4; ++n)
          acc[m][n] = __builtin_amdgcn_mfma_f32_16x16x32_bf16(afrag[m], bfrag[n], acc[m][n], 0, 0, 0);
    }
    __syncthreads();
  }

  // ---- fused epilogue: scores, exp-sums, diag terms ----
  const float lt = *p_log_tau;
  const float mg = *p_margin;
  const float marg = fmaxf(mg, 0.f);
  const float tau = 1.99f / (1.f + __expf(-lt)) + 0.01f;
  const float ninv_tau = -1.f / tau;
  const float C = marg;              // shift: scores <= marg, so exp(s-C) <= 1

  float yyj[4]; int gj[4];
  #pragma unroll
  for (int n = 0; n < 4; ++n) {
    gj[n] = blockCol + waveN * 64 + n * 16 + l15;   // C/D col = lane&15 (verified layout)
    yyj[n] = yy[gj[n]];
  }

  float s_total = 0.f, s_diag = 0.f, d_diag = 0.f;

  #pragma unroll
  for (int m = 0; m < 4; ++m) {
    #pragma unroll
    for (int r = 0; r < 4; ++r) {
      const int gi = blockRow + waveM * 64 + m * 16 + g4 * 4 + r;  // C/D row = (lane>>4)*4+reg
      const float xxi = xx[gi];
      const float omx = 1.f - xxi;
      float e_acc = 0.f;
      #pragma unroll
      for (int n = 0; n < 4; ++n) {
        const float xy = acc[m][n][r];
        const float sq = fmaxf(xxi + yyj[n] - 2.f * xy, 0.f);
        const float denom = fmaxf(omx * (1.f - yyj[n]), EPSF);
        float arg = 1.f + 2.f * sq / denom;
        arg = fmaxf(arg, 1.f + EPSF);
        const float dist = __logf(arg + sqrtf((arg - 1.f) * (arg + 1.f)));  // arccosh
        const bool isdiag = (gi == gj[n]);
        const float sc = dist * ninv_tau + (isdiag ? 0.f : marg);
        e_acc += __expf(sc - C);
        s_total += sc;
        if (isdiag) { s_diag += sc; d_diag += dist; }
      }
      // reduce exp-sum across the 16 lanes sharing this row
      e_acc += __shfl_xor(e_acc, 1);
      e_acc += __shfl_xor(e_acc, 2);
      e_acc += __shfl_xor(e_acc, 4);
      e_acc += __shfl_xor(e_acc, 8);
      if (l15 == 0) atomicAdd(&row_sumexp[gi], e_acc);
    }
  }

  #pragma unroll
  for (int off = 32; off; off >>= 1) {
    s_total += __shfl_down(s_total, off);
    s_diag  += __shfl_down(s_diag, off);
    d_diag  += __shfl_down(d_diag, off);
  }
  if (lane == 0) { red[wave][0] = s_total; red[wave][1] = s_diag; red[wave][2] = d_diag; }
  __syncthreads();
  if (tid == 0) {
    const float a0 = red[0][0] + red[1][0] + red[2][0] + red[3][0];
    const float a1 = red[0][1] + red[1][1] + red[2][1] + red[3][1];
    const float a2 = red[0][2] + red[1][2] + red[2][2] + red[3][2];
    atomicAdd(&accums[0], a0);   // sum of all scores
    atomicAdd(&accums[1], a1);   // sum of diagonal scores
    atomicAdd(&accums[2], a2);   // sum of diagonal dists
  }
}

// ---------------- finalize: log of row sums + linear combination ----------------
__global__ __launch_bounds__(1024) void finalize_kernel(
    const float* __restrict__ row_sumexp, const float* __restrict__ accums,
    const float* __restrict__ p_log_tau, const float* __restrict__ p_margin,
    float* __restrict__ out) {
  const int t = threadIdx.x;
  float lsum = 0.f;
  for (int i = t; i < BN; i += 1024) lsum += __logf(row_sumexp[i]);
  #pragma unroll
  for (int off = 32; off; off >>= 1) lsum += __shfl_down(lsum, off);
  __shared__ float red[16];
  if ((t & 63) == 0) red[t >> 6] = lsum;
  __syncthreads();
  if (t == 0) {
    float total = 0.f;
    #pragma unroll
    for (int w = 0; w < 16; ++w) total += red[w];
    const float lt = *p_log_tau;
    const float mg = *p_margin;
    const float marg = fmaxf(mg, 0.f);
    const float tau = 1.99f / (1.f + __expf(-lt)) + 0.01f;
    const float C = marg;
    const float mean_lse = total / (float)BN + C;
    const float loss = mean_lse
                     - (1.f - LSMOOTH) * (accums[1] / (float)BN)
                     - LSMOOTH * (accums[0] / ((float)BN * (float)BN));
    out[0] = loss;
    out[1] = accums[2] / (float)BN;   // pos_dist
    out[2] = tau;
    out[3] = mg;                      // maximum(margin, margin) == margin
  }
}

extern "C" void kernel_launch(void* const* d_in, const int* in_sizes, int n_in,
                              void* d_out, int out_size, void* d_ws, size_t ws_size,
                              hipStream_t stream) {
  const float* sign = (const float*)d_in[0];
  const float* text = (const float*)d_in[1];
  const float* p_log_tau = (const float*)d_in[2];
  const float* p_margin = (const float*)d_in[3];
  float* out = (float*)d_out;

  char* ws = (char*)d_ws;
  unsigned short* Abf = (unsigned short*)ws;                         // 16 MiB
  unsigned short* Bbf = (unsigned short*)(ws + (size_t)BN * DK * 2); // 16 MiB
  float* xx = (float*)(ws + (size_t)BN * DK * 4);
  float* yy = xx + BN;
  float* row_sumexp = yy + BN;
  float* accums = row_sumexp + BN;                                   // 3 floats

  hipMemsetAsync(row_sumexp, 0, (BN + 4) * sizeof(float), stream);
  prep_kernel<<<dim3(2 * BN), 256, 0, stream>>>(sign, text, Abf, Bbf, xx, yy);
  gemm_fused<<<dim3(BN / 128, BN / 128), 256, 0, stream>>>(
      Abf, Bbf, xx, yy, p_log_tau, p_margin, row_sumexp, accums);
  finalize_kernel<<<1, 1024, 0, stream>>>(row_sumexp, accums, p_log_tau, p_margin, out);
}